// Round 17
// baseline (212.087 us; speedup 1.0000x reference)
//
#include <hip/hip_runtime.h>
#include <hip/hip_bf16.h>

#define Bq    4
#define NPTS  16384
#define SPTS  2048
#define NCH   8
#define SCH   (SPTS/NCH)   // 256
#define CNTF  65536.0f
#define BNEPS 1e-5f

typedef unsigned short u16t;
typedef unsigned int   u32t;
typedef __attribute__((ext_vector_type(8))) short s16x8;
typedef __attribute__((ext_vector_type(4))) float f32x4;

#define AS1(p) ((const __attribute__((address_space(1))) void*)(p))
#define AS3(p) ((__attribute__((address_space(3))) void*)(p))

__device__ __forceinline__ float b2f(u16t u){
  union { u32t i; float f; } v; v.i = ((u32t)u) << 16; return v.f;
}
__device__ __forceinline__ u16t f2b(float f){
  __hip_bfloat16 h = __float2bfloat16(f);
  return *reinterpret_cast<u16t*>(&h);
}
__device__ __forceinline__ float lrelu(float x){ return x >= 0.0f ? x : 0.2f*x; }

// ---- stats f32 offsets: per-channel [sum,sumsq] pairs ----
#define ST_WG  0
#define ST_WX  128
#define ST_PSI 256
#define ST_BN1 272
#define ST_BN2 784

// ---- bf16 weight element offsets inside WB region ----
#define WOFF_C1 0
#define WOFF_C2 98304
#define WOFF_WG 131072
#define WOFF_WX 147456
#define WTOTAL  155648

// ---- ws byte offsets (time-disjoint aliasing; total ~84.6 MB) ----
#define O_STATS  0u
#define O_WB     8192u
#define O_PSIPRE 319488u        // 262144 B; first 128 KB doubles as packed-xyz2 sp
#define O_SP     O_PSIPRE
#define O_P2T    581632u        // 4 MB bf16 [B][S][256]; dead after interp
#define O_PART   O_P2T          // conv stats partials (2 x 512KB halves fit), used after interp
#define O_PART2  (O_P2T + 1048576u)
#define O_P1T    4775936u       // 16.7 MB bf16 [B][N][128]
#define O_INT    21553152u      // 33.5 MB bf16 [B][N][256] interp; h2t aliases later
#define O_H1     55107584u      // 33.5 MB bf16 [B][N][256] h1; bnrelu IN PLACE
#define O_PD     O_H1
#define O_PI     (O_H1 + 6291456u)
#define O_IDX3   (O_H1 + 12582912u)
#define O_W3     (O_H1 + 13369344u)
#define O_YG     O_H1
#define O_YX     (O_H1 + 8388608u)
#define O_H2     O_INT
// end = 55107584 + 33554432 = 88662016 B

// ---- pack xyz2 -> sp[B][S] = (2x,2y,2z,|s|^2): dot2 = 2*dot exactly ----
__global__ __launch_bounds__(256) void knn_prep_kernel(const float* __restrict__ xyz2, float4* __restrict__ sp){
  int i = blockIdx.x*256 + threadIdx.x;
  int b = i >> 11, s = i & (SPTS-1);
  float x = xyz2[(b*3+0)*SPTS+s];
  float y = xyz2[(b*3+1)*SPTS+s];
  float z = xyz2[(b*3+2)*SPTS+s];
  sp[i] = make_float4(2.0f*x, 2.0f*y, 2.0f*z, x*x+y*y+z*z);
}

// ---- 3-NN part 1: branchless sorted-triple insert, unroll-8-batched scalar loads ----
__global__ __launch_bounds__(256) void knn_part_kernel(const float* __restrict__ xyz1, const float4* __restrict__ sp,
                                                       float* __restrict__ pd, int* __restrict__ pi){
  const int b = blockIdx.z;
  const int c = blockIdx.y;
  const int n = blockIdx.x*256 + threadIdx.x;
  const float4* cp = sp + (size_t)b*SPTS + c*SCH;
  float px = xyz1[(b*3+0)*NPTS+n];
  float py = xyz1[(b*3+1)*NPTS+n];
  float pz = xyz1[(b*3+2)*NPTS+n];
  float s1 = px*px+py*py+pz*pz;
  float d0=3.4e38f, d1=3.4e38f, d2=3.4e38f;
  int   i0=0, i1=0, i2=0;
  const int cbase = c*SCH;
  #pragma unroll 8
  for (int s=0; s<SCH; ++s){
    float4 q = cp[s];
    float dot2 = fmaf(pz, q.z, fmaf(py, q.y, px*q.x));
    float key = (s1 + q.w) - dot2;
    int gi = cbase + s;
    bool c0 = key < d0, c1 = key < d1, c2 = key < d2;
    int ni2 = c1 ? i1 : (c2 ? gi : i2);
    int ni1 = c0 ? i0 : (c1 ? gi : i1);
    i0 = c0 ? gi : i0;
    float nd2 = fminf(d2, fmaxf(d1, key));
    d1 = __builtin_amdgcn_fmed3f(d0, d1, key);
    d0 = fminf(d0, key);
    d2 = nd2; i1 = ni1; i2 = ni2;
  }
  size_t base = (((size_t)b*NPTS + n)*NCH + c)*3;
  pd[base]=d0; pd[base+1]=d1; pd[base+2]=d2;
  pi[base]=i0; pi[base+1]=i1; pi[base+2]=i2;
}

// ---- 3-NN part 2: merge NCH partial top-3 lists ----
__global__ __launch_bounds__(256) void knn_merge_kernel(const float* __restrict__ pd, const int* __restrict__ pi,
                                                        int* __restrict__ idx3, float* __restrict__ w3){
  const int p = blockIdx.x*256 + threadIdx.x;
  const float* dp = pd + (size_t)p*NCH*3;
  const int*   ip = pi + (size_t)p*NCH*3;
  float d0=3.4e38f, d1=3.4e38f, d2=3.4e38f;
  int   i0=0, i1=0, i2=0;
  #pragma unroll
  for (int k=0; k<NCH*3; ++k){
    float key = dp[k]; int gi = ip[k];
    bool c0 = key < d0, c1 = key < d1, c2 = key < d2;
    int ni2 = c1 ? i1 : (c2 ? gi : i2);
    int ni1 = c0 ? i0 : (c1 ? gi : i1);
    i0 = c0 ? gi : i0;
    float nd2 = fminf(d2, fmaxf(d1, key));
    d1 = __builtin_amdgcn_fmed3f(d0, d1, key);
    d0 = fminf(d0, key);
    d2 = nd2; i1 = ni1; i2 = ni2;
  }
  float r0=1.0f/(d0+1e-8f), r1=1.0f/(d1+1e-8f), r2=1.0f/(d2+1e-8f);
  float rs = r0+r1+r2;
  size_t base = (size_t)p*3;
  idx3[base]=i0; idx3[base+1]=i1; idx3[base+2]=i2;
  w3[base]=r0/rs; w3[base+1]=r1/rs; w3[base+2]=r2/rs;
}

// ---- tiled transpose: src f32 [B][C][NN] -> dst bf16 [B][NN][C] ----
template<int C, int NN>
__global__ __launch_bounds__(256) void tpose_kernel(const float* __restrict__ src, u16t* __restrict__ dst){
  __shared__ float tile[64][65];
  const int n0 = blockIdx.x * 64;
  const int c0 = blockIdx.y * 64;
  const int b  = blockIdx.z;
  const int t  = threadIdx.x;
  #pragma unroll
  for (int i = 0; i < 16; ++i){
    int idx = t + i*256;
    int cc = idx >> 6, nn = idx & 63;
    tile[cc][nn] = src[((size_t)b*C + c0 + cc)*NN + n0 + nn];
  }
  __syncthreads();
  #pragma unroll
  for (int i = 0; i < 16; ++i){
    int idx = t + i*256;
    int nn = idx >> 6, cc = idx & 63;
    dst[((size_t)b*NN + n0 + nn)*C + c0 + cc] = f2b(tile[cc][nn]);
  }
}

// ---- weight convert f32 -> bf16 into WB ----
__global__ __launch_bounds__(256) void wcvt_kernel(const float* __restrict__ w1, const float* __restrict__ w2,
                                                   const float* __restrict__ wg, const float* __restrict__ wx,
                                                   u16t* __restrict__ wb){
  int i = blockIdx.x*256 + threadIdx.x;
  if (i >= WTOTAL) return;
  float v;
  if      (i < WOFF_C2) v = w1[i];
  else if (i < WOFF_WG) v = w2[i - WOFF_C2];
  else if (i < WOFF_WX) v = wg[i - WOFF_WG];
  else                  v = wx[i - WOFF_WX];
  wb[i] = f2b(v);
}

// ---- interp: half-wave (32 lanes) per point ----
__global__ __launch_bounds__(256) void interp_kernel(const u16t* __restrict__ p2t, const int* __restrict__ idx3,
                                                     const float* __restrict__ w3, u16t* __restrict__ it){
  const int t = threadIdx.x;
  const int pid = blockIdx.x*8 + (t >> 5);
  const int l = t & 31;
  const int b = pid >> 14;
  size_t pb = (size_t)pid*3;
  int i0 = idx3[pb], i1 = idx3[pb+1], i2 = idx3[pb+2];
  float w0 = w3[pb], w1 = w3[pb+1], w2 = w3[pb+2];
  const u16t* r0 = p2t + ((size_t)b*SPTS + i0)*256 + l*8;
  const u16t* r1 = p2t + ((size_t)b*SPTS + i1)*256 + l*8;
  const u16t* r2 = p2t + ((size_t)b*SPTS + i2)*256 + l*8;
  uint4 q0 = *reinterpret_cast<const uint4*>(r0);
  uint4 q1 = *reinterpret_cast<const uint4*>(r1);
  uint4 q2 = *reinterpret_cast<const uint4*>(r2);
  const u32t* a0 = reinterpret_cast<const u32t*>(&q0);
  const u32t* a1 = reinterpret_cast<const u32t*>(&q1);
  const u32t* a2 = reinterpret_cast<const u32t*>(&q2);
  u32t ow[4];
  #pragma unroll
  for (int j = 0; j < 4; ++j){
    u32t u0 = a0[j], u1 = a1[j], u2 = a2[j];
    float lo = fmaf(w2, b2f((u16t)u2), fmaf(w1, b2f((u16t)u1), w0*b2f((u16t)u0)));
    float hi = fmaf(w2, b2f((u16t)(u2>>16)), fmaf(w1, b2f((u16t)(u1>>16)), w0*b2f((u16t)(u0>>16))));
    ow[j] = (u32t)f2b(lo) | ((u32t)f2b(hi) << 16);
  }
  *reinterpret_cast<uint4*>(it + (size_t)pid*256 + l*8) = make_uint4(ow[0], ow[1], ow[2], ow[3]);
}

// ---- MFMA conv1x1: OUT channels into row-stride YSTR (M-split support), TILE=128 ----
template<int CIN, int OUT, int YSTR, int TILE, bool SPLIT>
__global__ __launch_bounds__(256, 1) void mfma_conv_kernel(const u16t* __restrict__ xa, const u16t* __restrict__ xb,
                                                           const u16t* __restrict__ W, const float* __restrict__ bias,
                                                           u16t* __restrict__ y, float* __restrict__ partial,
                                                           const float* __restrict__ psipre, const float* __restrict__ stpsi,
                                                           const float* __restrict__ pbn_g, const float* __restrict__ pbn_b){
  constexpr int MW = OUT/4;
  constexpr int MF = MW/16;
  constexpr int NC = CIN/64;
  constexpr int NF = TILE/16;
  constexpr int NH = TILE/64;
  constexpr int SI = TILE/32;
  constexpr int CSTR = OUT + 8;
  constexpr int SBUF = TILE*64;
  constexpr int LDSE = (64*CSTR > 2*SBUF) ? 64*CSTR : 2*SBUF;
  __shared__ u16t lds[LDSE];
  const int bid = blockIdx.x;
  const int tpb = NPTS/TILE;
  const int b = bid / tpb;
  const int n0 = (bid % tpb) * TILE;
  const int wv = threadIdx.x >> 6;
  const int lane = threadIdx.x & 63;
  const int lr = lane & 15;
  const int kg = lane >> 4;
  const int m0 = wv * MW;
  const int t = threadIdx.x;

  float psiv[NF];
  if (SPLIT){
    float m  = stpsi[0]*(1.0f/CNTF);
    float vv = fmaxf(stpsi[1]*(1.0f/CNTF) - m*m, 0.0f);
    float iv = 1.0f/sqrtf(vv + BNEPS);
    float ap = pbn_g[0]*iv;
    float bp = pbn_b[0] - m*ap;
    #pragma unroll
    for (int nf = 0; nf < NF; ++nf){
      float z = fmaf(psipre[b*NPTS + n0 + nf*16 + lr], ap, bp);
      psiv[nf] = 1.0f/(1.0f + expf(-z));
    }
  }

  f32x4 acc[MF][NF];
  #pragma unroll
  for (int mf = 0; mf < MF; ++mf)
    #pragma unroll
    for (int nf = 0; nf < NF; ++nf){ acc[mf][nf][0]=0.f; acc[mf][nf][1]=0.f; acc[mf][nf][2]=0.f; acc[mf][nf][3]=0.f; }

  const u16t* wrow[MF];
  #pragma unroll
  for (int mf = 0; mf < MF; ++mf)
    wrow[mf] = W + (size_t)(m0 + mf*16 + lr)*CIN + kg*8;

  const int prow0 = wv*(TILE/4) + (lane>>3);
  const int gslot = (lane & 7) ^ ((lane >> 3) & 7);
  int rdoff[2][NF];
  #pragma unroll
  for (int ks = 0; ks < 2; ++ks)
    #pragma unroll
    for (int nf = 0; nf < NF; ++nf)
      rdoff[ks][nf] = (nf*16 + lr)*64 + (((ks*4 + kg) ^ (lr & 7)) << 3);

  auto stage = [&](int c, int buf){
    #pragma unroll
    for (int i = 0; i < SI; ++i){
      int p = prow0 + i*8;
      const u16t* g;
      if (SPLIT){
        if (c < 2) g = xa + ((size_t)b*NPTS + n0 + p)*128 + c*64     + gslot*8;
        else       g = xb + ((size_t)b*NPTS + n0 + p)*256 + (c-2)*64 + gslot*8;
      } else {
        g = xa + ((size_t)b*NPTS + n0 + p)*CIN + c*64 + gslot*8;
      }
      u16t* l = lds + buf*SBUF + (wv*(TILE/4) + i*8)*64;
      __builtin_amdgcn_global_load_lds(AS1(g), AS3(l), 16, 0, 0);
    }
  };

  stage(0, 0);
  __syncthreads();
  #pragma unroll
  for (int c = 0; c < NC; ++c){
    if (c + 1 < NC) stage(c+1, (c+1)&1);
    #pragma unroll
    for (int ks = 0; ks < 2; ++ks){
      const int k0 = c*2 + ks;
      s16x8 av[MF];
      #pragma unroll
      for (int mf = 0; mf < MF; ++mf)
        av[mf] = *reinterpret_cast<const s16x8*>(wrow[mf] + k0*32);
      #pragma unroll
      for (int h = 0; h < NF/4; ++h){
        s16x8 bv[4];
        #pragma unroll
        for (int j = 0; j < 4; ++j)
          bv[j] = *reinterpret_cast<const s16x8*>(lds + (c&1)*SBUF + rdoff[ks][h*4+j]);
        #pragma unroll
        for (int mf = 0; mf < MF; ++mf)
          #pragma unroll
          for (int j = 0; j < 4; ++j)
            acc[mf][h*4+j] = __builtin_amdgcn_mfma_f32_16x16x32_bf16(av[mf], bv[j], acc[mf][h*4+j], 0, 0, 0);
      }
    }
    if (SPLIT && c == 1){
      #pragma unroll
      for (int mf = 0; mf < MF; ++mf)
        #pragma unroll
        for (int nf = 0; nf < NF; ++nf){
          acc[mf][nf][0] *= psiv[nf]; acc[mf][nf][1] *= psiv[nf];
          acc[mf][nf][2] *= psiv[nf]; acc[mf][nf][3] *= psiv[nf];
        }
    }
    __syncthreads();
  }

  #pragma unroll
  for (int mf = 0; mf < MF; ++mf){
    int mb = m0 + mf*16 + kg*4;
    float4 bs = *reinterpret_cast<const float4*>(bias + mb);
    float s0=0.f,s1=0.f,s2=0.f,s3=0.f,q0=0.f,q1=0.f,q2=0.f,q3=0.f;
    #pragma unroll
    for (int nf = 0; nf < NF; ++nf){
      float v0 = acc[mf][nf][0] + bs.x;
      float v1 = acc[mf][nf][1] + bs.y;
      float v2 = acc[mf][nf][2] + bs.z;
      float v3 = acc[mf][nf][3] + bs.w;
      acc[mf][nf][0]=v0; acc[mf][nf][1]=v1; acc[mf][nf][2]=v2; acc[mf][nf][3]=v3;
      s0+=v0; q0+=v0*v0; s1+=v1; q1+=v1*v1;
      s2+=v2; q2+=v2*v2; s3+=v3; q3+=v3*v3;
    }
    #pragma unroll
    for (int o = 1; o < 16; o <<= 1){
      s0 += __shfl_xor(s0, o); s1 += __shfl_xor(s1, o);
      s2 += __shfl_xor(s2, o); s3 += __shfl_xor(s3, o);
      q0 += __shfl_xor(q0, o); q1 += __shfl_xor(q1, o);
      q2 += __shfl_xor(q2, o); q3 += __shfl_xor(q3, o);
    }
    if (lr == 0){
      float* pp = partial + (size_t)bid*(OUT*2) + mb*2;
      pp[0]=s0; pp[1]=q0; pp[2]=s1; pp[3]=q1;
      pp[4]=s2; pp[5]=q2; pp[6]=s3; pp[7]=q3;
    }
  }

  constexpr int CH8 = OUT/8;
  #pragma unroll
  for (int h = 0; h < NH; ++h){
    __syncthreads();
    #pragma unroll
    for (int mf = 0; mf < MF; ++mf){
      int mb = m0 + mf*16 + kg*4;
      #pragma unroll
      for (int j = 0; j < 4; ++j){
        int row = j*16 + lr;
        f32x4 v = acc[mf][h*4+j];
        uint2 pv;
        pv.x = (u32t)f2b(v[0]) | ((u32t)f2b(v[1]) << 16);
        pv.y = (u32t)f2b(v[2]) | ((u32t)f2b(v[3]) << 16);
        *reinterpret_cast<uint2*>(&lds[row*CSTR + mb]) = pv;
      }
    }
    __syncthreads();
    #pragma unroll
    for (int i = 0; i < (64*CH8)/256; ++i){
      int idx = t + i*256;
      int row = idx / CH8, c8 = idx % CH8;
      uint4 v = *reinterpret_cast<const uint4*>(&lds[row*CSTR + c8*8]);
      *reinterpret_cast<uint4*>(y + ((size_t)b*NPTS + n0 + h*64 + row)*YSTR + c8*8) = v;
    }
  }
}

// ---- reduce conv partials [NBLK][E] -> stats[E] (no atomics) ----
template<int E, int NBLK>
__global__ __launch_bounds__(256) void reduce_stats_kernel(const float* __restrict__ p, float* __restrict__ st){
  __shared__ float ls[8][32];
  const int t = threadIdx.x;
  const int kq = t >> 5, es = t & 31;
  const int e = blockIdx.x*32 + es;
  constexpr int R = NBLK/8;
  float s = 0.f;
  const float* pp = p + (size_t)kq*R*E + e;
  #pragma unroll 16
  for (int i = 0; i < R; ++i) s += pp[(size_t)i*E];
  ls[kq][es] = s;
  __syncthreads();
  if (kq == 0){
    st[e] = ((ls[0][es]+ls[1][es])+(ls[2][es]+ls[3][es]))
          + ((ls[4][es]+ls[5][es])+(ls[6][es]+ls[7][es]));
  }
}

// ---- gate ----
__global__ __launch_bounds__(256) void gate_kernel(const u16t* __restrict__ yg, const u16t* __restrict__ yx,
                                                   const float* __restrict__ stg, const float* __restrict__ stx,
                                                   const float* __restrict__ wg_bn_g, const float* __restrict__ wg_bn_b,
                                                   const float* __restrict__ wx_bn_g, const float* __restrict__ wx_bn_b,
                                                   const float* __restrict__ psi_w, const float* __restrict__ psi_b,
                                                   float* __restrict__ psipre, float* __restrict__ stpsi){
  __shared__ float lag[64], lbg[64], lax[64], lbx[64], lpw[64];
  __shared__ float red[8];
  const int t = threadIdx.x;
  if (t < 64){
    float m  = stg[t*2] * (1.0f/CNTF);
    float vv = fmaxf(stg[t*2+1]*(1.0f/CNTF) - m*m, 0.0f);
    float iv = 1.0f/sqrtf(vv + BNEPS);
    float gm = wg_bn_g[t];
    lag[t] = gm*iv; lbg[t] = wg_bn_b[t] - m*gm*iv;
    m  = stx[t*2] * (1.0f/CNTF);
    vv = fmaxf(stx[t*2+1]*(1.0f/CNTF) - m*m, 0.0f);
    iv = 1.0f/sqrtf(vv + BNEPS);
    gm = wx_bn_g[t];
    lax[t] = gm*iv; lbx[t] = wx_bn_b[t] - m*gm*iv;
    lpw[t] = psi_w[t];
  }
  __syncthreads();
  const int p = blockIdx.x*256 + t;
  const u16t* rg = yg + (size_t)p*64;
  const u16t* rx = yx + (size_t)p*64;
  float acc = psi_b[0];
  #pragma unroll
  for (int u = 0; u < 8; ++u){
    uint4 qg = *reinterpret_cast<const uint4*>(rg + u*8);
    uint4 qx = *reinterpret_cast<const uint4*>(rx + u*8);
    const u32t* g4 = reinterpret_cast<const u32t*>(&qg);
    const u32t* x4 = reinterpret_cast<const u32t*>(&qx);
    #pragma unroll
    for (int e = 0; e < 4; ++e){
      int j = u*8 + e*2;
      float gv0 = fmaf(b2f((u16t)g4[e]),        lag[j],   lbg[j]);
      float xv0 = fmaf(b2f((u16t)x4[e]),        lax[j],   lbx[j]);
      float gv1 = fmaf(b2f((u16t)(g4[e]>>16)),  lag[j+1], lbg[j+1]);
      float xv1 = fmaf(b2f((u16t)(x4[e]>>16)),  lax[j+1], lbx[j+1]);
      acc = fmaf(lpw[j],   lrelu(gv0 + xv0), acc);
      acc = fmaf(lpw[j+1], lrelu(gv1 + xv1), acc);
    }
  }
  psipre[p] = acc;
  float s = acc, q = acc*acc;
  #pragma unroll
  for (int o = 32; o; o >>= 1){ s += __shfl_xor(s, o); q += __shfl_xor(q, o); }
  if ((t & 63) == 0){ red[(t>>6)*2] = s; red[(t>>6)*2+1] = q; }
  __syncthreads();
  if (t == 0){
    atomicAdd(&stpsi[0], red[0]+red[2]+red[4]+red[6]);
    atomicAdd(&stpsi[1], red[1]+red[3]+red[5]+red[7]);
  }
}

// ---- bn1 + lrelu in place on h1 [P][256] bf16 ----
__global__ __launch_bounds__(256) void bnrelu256_kernel(u16t* __restrict__ x, const float* __restrict__ st,
                                                        const float* __restrict__ g, const float* __restrict__ bb){
  __shared__ float sa[256], sc[256];
  const int t = threadIdx.x;
  {
    float m  = st[t*2]*(1.0f/CNTF);
    float vv = fmaxf(st[t*2+1]*(1.0f/CNTF) - m*m, 0.0f);
    float iv = 1.0f/sqrtf(vv + BNEPS);
    float gm = g[t];
    sa[t] = gm*iv; sc[t] = bb[t] - m*gm*iv;
  }
  __syncthreads();
  size_t e4 = ((size_t)blockIdx.x*256 + t)*4;
  int c0 = (int)(e4 & 255);
  uint2 v = *reinterpret_cast<uint2*>(x + e4);
  float f0 = lrelu(fmaf(b2f((u16t)v.x),        sa[c0],   sc[c0]));
  float f1 = lrelu(fmaf(b2f((u16t)(v.x>>16)),  sa[c0+1], sc[c0+1]));
  float f2 = lrelu(fmaf(b2f((u16t)v.y),        sa[c0+2], sc[c0+2]));
  float f3 = lrelu(fmaf(b2f((u16t)(v.y>>16)),  sa[c0+3], sc[c0+3]));
  v.x = (u32t)f2b(f0) | ((u32t)f2b(f1) << 16);
  v.y = (u32t)f2b(f2) | ((u32t)f2b(f3) << 16);
  *reinterpret_cast<uint2*>(x + e4) = v;
}

// ---- final: out[b][m][n] f32 = lrelu(bn2(h2[b][n][m])) via LDS tile transpose ----
__global__ __launch_bounds__(256) void final_kernel(const u16t* __restrict__ h2, const float* __restrict__ st,
                                                    const float* __restrict__ g, const float* __restrict__ bb,
                                                    float* __restrict__ out){
  __shared__ float am[128], cm[128];
  __shared__ float tile[64][129];
  const int t = threadIdx.x;
  if (t < 128){
    float m  = st[t*2]*(1.0f/CNTF);
    float vv = fmaxf(st[t*2+1]*(1.0f/CNTF) - m*m, 0.0f);
    float iv = 1.0f/sqrtf(vv + BNEPS);
    float gm = g[t];
    am[t] = gm*iv; cm[t] = bb[t] - m*gm*iv;
  }
  __syncthreads();
  const int n0 = blockIdx.x * 64;
  const int b  = blockIdx.y;
  #pragma unroll
  for (int i = 0; i < 32; ++i){
    int idx = t + i*256;
    int mm = idx & 127, nn = idx >> 7;
    float v = fmaf(b2f(h2[((size_t)b*NPTS + n0 + nn)*128 + mm]), am[mm], cm[mm]);
    tile[nn][mm] = lrelu(v);
  }
  __syncthreads();
  #pragma unroll
  for (int i = 0; i < 32; ++i){
    int idx = t + i*256;
    int nn = idx & 63, mm = idx >> 6;
    out[((size_t)(b*128 + mm))*NPTS + n0 + nn] = tile[nn][mm];
  }
}

extern "C" void kernel_launch(void* const* d_in, const int* in_sizes, int n_in,
                              void* d_out, int out_size, void* d_ws, size_t ws_size,
                              hipStream_t stream){
  const float* xyz1    = (const float*)d_in[0];
  const float* xyz2    = (const float*)d_in[1];
  const float* points1 = (const float*)d_in[2];
  const float* points2 = (const float*)d_in[3];
  const float* conv1_w = (const float*)d_in[4];
  const float* conv1_b = (const float*)d_in[5];
  const float* bn1_g   = (const float*)d_in[6];
  const float* bn1_b   = (const float*)d_in[7];
  const float* conv2_w = (const float*)d_in[8];
  const float* conv2_b = (const float*)d_in[9];
  const float* bn2_g   = (const float*)d_in[10];
  const float* bn2_b   = (const float*)d_in[11];
  const float* wg_w    = (const float*)d_in[12];
  const float* wg_b    = (const float*)d_in[13];
  const float* wg_bn_g = (const float*)d_in[14];
  const float* wg_bn_b = (const float*)d_in[15];
  const float* wx_w    = (const float*)d_in[16];
  const float* wx_b    = (const float*)d_in[17];
  const float* wx_bn_g = (const float*)d_in[18];
  const float* wx_bn_b = (const float*)d_in[19];
  const float* psi_w   = (const float*)d_in[20];
  const float* psi_b   = (const float*)d_in[21];
  const float* psi_bn_g= (const float*)d_in[22];
  const float* psi_bn_b= (const float*)d_in[23];

  char* ws = (char*)d_ws;
  float* stats  = (float*)(ws + O_STATS);
  u16t*  wb     = (u16t*)(ws + O_WB);
  float* psipre = (float*)(ws + O_PSIPRE);
  float4* sp    = (float4*)(ws + O_SP);
  u16t*  p2t    = (u16t*)(ws + O_P2T);
  float* part   = (float*)(ws + O_PART);
  float* part2  = (float*)(ws + O_PART2);
  u16t*  p1t    = (u16t*)(ws + O_P1T);
  u16t*  itp    = (u16t*)(ws + O_INT);
  u16t*  h1t    = (u16t*)(ws + O_H1);
  float* pd     = (float*)(ws + O_PD);
  int*   pi     = (int*)(ws + O_PI);
  int*   idx3   = (int*)(ws + O_IDX3);
  float* w3     = (float*)(ws + O_W3);
  u16t*  ygt    = (u16t*)(ws + O_YG);
  u16t*  yxt    = (u16t*)(ws + O_YX);
  u16t*  h2t    = (u16t*)(ws + O_H2);

  hipMemsetAsync(ws + O_STATS, 0, 8192, stream);

  knn_prep_kernel<<<(Bq*SPTS)/256, 256, 0, stream>>>(xyz2, sp);
  knn_part_kernel<<<dim3(NPTS/256, NCH, Bq), 256, 0, stream>>>(xyz1, sp, pd, pi);
  knn_merge_kernel<<<(Bq*NPTS)/256, 256, 0, stream>>>(pd, pi, idx3, w3);
  tpose_kernel<256, SPTS><<<dim3(SPTS/64, 4, Bq), 256, 0, stream>>>(points2, p2t);
  interp_kernel<<<(Bq*NPTS)/8, 256, 0, stream>>>(p2t, idx3, w3, itp);
  tpose_kernel<128, NPTS><<<dim3(NPTS/64, 2, Bq), 256, 0, stream>>>(points1, p1t);
  wcvt_kernel<<<(WTOTAL+255)/256, 256, 0, stream>>>(conv1_w, conv2_w, wg_w, wx_w, wb);

  mfma_conv_kernel<256, 64, 64, 128, false><<<Bq*(NPTS/128), 256, 0, stream>>>(itp, nullptr, wb+WOFF_WG, wg_b, ygt, part,
                                                                               nullptr, nullptr, nullptr, nullptr);
  reduce_stats_kernel<128, 512><<<4, 256, 0, stream>>>(part, stats+ST_WG);
  mfma_conv_kernel<128, 64, 64, 128, false><<<Bq*(NPTS/128), 256, 0, stream>>>(p1t, nullptr, wb+WOFF_WX, wx_b, yxt, part,
                                                                               nullptr, nullptr, nullptr, nullptr);
  reduce_stats_kernel<128, 512><<<4, 256, 0, stream>>>(part, stats+ST_WX);
  gate_kernel<<<256, 256, 0, stream>>>(ygt, yxt, stats+ST_WG, stats+ST_WX,
                                       wg_bn_g, wg_bn_b, wx_bn_g, wx_bn_b,
                                       psi_w, psi_b, psipre, stats+ST_PSI);

  // conv1 M-split: two OUT=128 dispatches into interleaved [P][256] rows (YSTR=256)
  mfma_conv_kernel<384, 128, 256, 128, true><<<Bq*(NPTS/128), 256, 0, stream>>>(
      p1t, itp, wb+WOFF_C1, conv1_b, h1t, part,
      psipre, stats+ST_PSI, psi_bn_g, psi_bn_b);
  mfma_conv_kernel<384, 128, 256, 128, true><<<Bq*(NPTS/128), 256, 0, stream>>>(
      p1t, itp, wb+WOFF_C1 + 128*384, conv1_b + 128, h1t + 128, part2,
      psipre, stats+ST_PSI, psi_bn_g, psi_bn_b);
  reduce_stats_kernel<256, 512><<<8, 256, 0, stream>>>(part,  stats+ST_BN1);
  reduce_stats_kernel<256, 512><<<8, 256, 0, stream>>>(part2, stats+ST_BN1+256);
  bnrelu256_kernel<<<16384, 256, 0, stream>>>(h1t, stats+ST_BN1, bn1_g, bn1_b);

  mfma_conv_kernel<256, 128, 128, 128, false><<<Bq*(NPTS/128), 256, 0, stream>>>(h1t, nullptr, wb+WOFF_C2, conv2_b, h2t, part,
                                                                                 nullptr, nullptr, nullptr, nullptr);
  reduce_stats_kernel<256, 512><<<8, 256, 0, stream>>>(part, stats+ST_BN2);
  final_kernel<<<dim3(NPTS/64, Bq), 256, 0, stream>>>(h2t, stats+ST_BN2, bn2_g, bn2_b, (float*)d_out);
}

// Round 18
// 211.027 us; speedup vs baseline: 1.0050x; 1.0050x over previous
//
#include <hip/hip_runtime.h>
#include <hip/hip_bf16.h>

#define Bq    4
#define NPTS  16384
#define SPTS  2048
#define NCH   8
#define SCH   (SPTS/NCH)   // 256
#define CNTF  65536.0f
#define BNEPS 1e-5f

typedef unsigned short u16t;
typedef unsigned int   u32t;
typedef __attribute__((ext_vector_type(8))) short s16x8;
typedef __attribute__((ext_vector_type(4))) float f32x4;

#define AS1(p) ((const __attribute__((address_space(1))) void*)(p))
#define AS3(p) ((__attribute__((address_space(3))) void*)(p))

__device__ __forceinline__ float b2f(u16t u){
  union { u32t i; float f; } v; v.i = ((u32t)u) << 16; return v.f;
}
__device__ __forceinline__ u16t f2b(float f){
  __hip_bfloat16 h = __float2bfloat16(f);
  return *reinterpret_cast<u16t*>(&h);
}
__device__ __forceinline__ float lrelu(float x){ return x >= 0.0f ? x : 0.2f*x; }

// ---- stats f32 offsets: per-channel [sum,sumsq] pairs ----
#define ST_WG  0
#define ST_WX  128
#define ST_PSI 256
#define ST_BN1 272
#define ST_BN2 784

// ---- bf16 weight element offsets inside WB region ----
#define WOFF_C1 0
#define WOFF_C2 98304
#define WOFF_WG 131072
#define WOFF_WX 147456
#define WTOTAL  155648

// ---- ws byte offsets (time-disjoint aliasing; total ~84.6 MB) ----
#define O_STATS  0u
#define O_WB     8192u
#define O_PSIPRE 319488u        // 262144 B; first 128 KB doubles as packed-xyz2 sp
#define O_SP     O_PSIPRE
#define O_P2T    581632u        // 4 MB bf16 [B][S][256]; dead after interp
#define O_PART   O_P2T          // conv stats partials (2 halves x 512KB fit), used after interp
#define O_P1T    4775936u       // 16.7 MB bf16 [B][N][128]
#define O_INT    21553152u      // 33.5 MB bf16 [B][N][256] interp; h2t aliases later
#define O_H1     55107584u      // 33.5 MB bf16 [B][N][256] h1; bnrelu IN PLACE
#define O_PD     O_H1
#define O_PI     (O_H1 + 6291456u)
#define O_IDX3   (O_H1 + 12582912u)
#define O_W3     (O_H1 + 13369344u)
#define O_YG     O_H1
#define O_YX     (O_H1 + 8388608u)
#define O_H2     O_INT
// end = 55107584 + 33554432 = 88662016 B

// ---- pack xyz2 -> sp[B][S] = (2x,2y,2z,|s|^2): dot2 = 2*dot exactly ----
__global__ __launch_bounds__(256) void knn_prep_kernel(const float* __restrict__ xyz2, float4* __restrict__ sp){
  int i = blockIdx.x*256 + threadIdx.x;
  int b = i >> 11, s = i & (SPTS-1);
  float x = xyz2[(b*3+0)*SPTS+s];
  float y = xyz2[(b*3+1)*SPTS+s];
  float z = xyz2[(b*3+2)*SPTS+s];
  sp[i] = make_float4(2.0f*x, 2.0f*y, 2.0f*z, x*x+y*y+z*z);
}

// ---- 3-NN part 1: branchless sorted-triple insert, unroll-8-batched scalar loads ----
__global__ __launch_bounds__(256) void knn_part_kernel(const float* __restrict__ xyz1, const float4* __restrict__ sp,
                                                       float* __restrict__ pd, int* __restrict__ pi){
  const int b = blockIdx.z;
  const int c = blockIdx.y;
  const int n = blockIdx.x*256 + threadIdx.x;
  const float4* cp = sp + (size_t)b*SPTS + c*SCH;
  float px = xyz1[(b*3+0)*NPTS+n];
  float py = xyz1[(b*3+1)*NPTS+n];
  float pz = xyz1[(b*3+2)*NPTS+n];
  float s1 = px*px+py*py+pz*pz;
  float d0=3.4e38f, d1=3.4e38f, d2=3.4e38f;
  int   i0=0, i1=0, i2=0;
  const int cbase = c*SCH;
  #pragma unroll 8
  for (int s=0; s<SCH; ++s){
    float4 q = cp[s];
    float dot2 = fmaf(pz, q.z, fmaf(py, q.y, px*q.x));
    float key = (s1 + q.w) - dot2;
    int gi = cbase + s;
    bool c0 = key < d0, c1 = key < d1, c2 = key < d2;
    int ni2 = c1 ? i1 : (c2 ? gi : i2);
    int ni1 = c0 ? i0 : (c1 ? gi : i1);
    i0 = c0 ? gi : i0;
    float nd2 = fminf(d2, fmaxf(d1, key));
    d1 = __builtin_amdgcn_fmed3f(d0, d1, key);
    d0 = fminf(d0, key);
    d2 = nd2; i1 = ni1; i2 = ni2;
  }
  size_t base = (((size_t)b*NPTS + n)*NCH + c)*3;
  pd[base]=d0; pd[base+1]=d1; pd[base+2]=d2;
  pi[base]=i0; pi[base+1]=i1; pi[base+2]=i2;
}

// ---- 3-NN part 2: merge NCH partial top-3 lists ----
__global__ __launch_bounds__(256) void knn_merge_kernel(const float* __restrict__ pd, const int* __restrict__ pi,
                                                        int* __restrict__ idx3, float* __restrict__ w3){
  const int p = blockIdx.x*256 + threadIdx.x;
  const float* dp = pd + (size_t)p*NCH*3;
  const int*   ip = pi + (size_t)p*NCH*3;
  float d0=3.4e38f, d1=3.4e38f, d2=3.4e38f;
  int   i0=0, i1=0, i2=0;
  #pragma unroll
  for (int k=0; k<NCH*3; ++k){
    float key = dp[k]; int gi = ip[k];
    bool c0 = key < d0, c1 = key < d1, c2 = key < d2;
    int ni2 = c1 ? i1 : (c2 ? gi : i2);
    int ni1 = c0 ? i0 : (c1 ? gi : i1);
    i0 = c0 ? gi : i0;
    float nd2 = fminf(d2, fmaxf(d1, key));
    d1 = __builtin_amdgcn_fmed3f(d0, d1, key);
    d0 = fminf(d0, key);
    d2 = nd2; i1 = ni1; i2 = ni2;
  }
  float r0=1.0f/(d0+1e-8f), r1=1.0f/(d1+1e-8f), r2=1.0f/(d2+1e-8f);
  float rs = r0+r1+r2;
  size_t base = (size_t)p*3;
  idx3[base]=i0; idx3[base+1]=i1; idx3[base+2]=i2;
  w3[base]=r0/rs; w3[base+1]=r1/rs; w3[base+2]=r2/rs;
}

// ---- tiled transpose: src f32 [B][C][NN] -> dst bf16 [B][NN][C] ----
template<int C, int NN>
__global__ __launch_bounds__(256) void tpose_kernel(const float* __restrict__ src, u16t* __restrict__ dst){
  __shared__ float tile[64][65];
  const int n0 = blockIdx.x * 64;
  const int c0 = blockIdx.y * 64;
  const int b  = blockIdx.z;
  const int t  = threadIdx.x;
  #pragma unroll
  for (int i = 0; i < 16; ++i){
    int idx = t + i*256;
    int cc = idx >> 6, nn = idx & 63;
    tile[cc][nn] = src[((size_t)b*C + c0 + cc)*NN + n0 + nn];
  }
  __syncthreads();
  #pragma unroll
  for (int i = 0; i < 16; ++i){
    int idx = t + i*256;
    int nn = idx >> 6, cc = idx & 63;
    dst[((size_t)b*NN + n0 + nn)*C + c0 + cc] = f2b(tile[cc][nn]);
  }
}

// ---- weight convert f32 -> bf16 into WB ----
__global__ __launch_bounds__(256) void wcvt_kernel(const float* __restrict__ w1, const float* __restrict__ w2,
                                                   const float* __restrict__ wg, const float* __restrict__ wx,
                                                   u16t* __restrict__ wb){
  int i = blockIdx.x*256 + threadIdx.x;
  if (i >= WTOTAL) return;
  float v;
  if      (i < WOFF_C2) v = w1[i];
  else if (i < WOFF_WG) v = w2[i - WOFF_C2];
  else if (i < WOFF_WX) v = wg[i - WOFF_WG];
  else                  v = wx[i - WOFF_WX];
  wb[i] = f2b(v);
}

// ---- interp: half-wave (32 lanes) per point ----
__global__ __launch_bounds__(256) void interp_kernel(const u16t* __restrict__ p2t, const int* __restrict__ idx3,
                                                     const float* __restrict__ w3, u16t* __restrict__ it){
  const int t = threadIdx.x;
  const int pid = blockIdx.x*8 + (t >> 5);
  const int l = t & 31;
  const int b = pid >> 14;
  size_t pb = (size_t)pid*3;
  int i0 = idx3[pb], i1 = idx3[pb+1], i2 = idx3[pb+2];
  float w0 = w3[pb], w1 = w3[pb+1], w2 = w3[pb+2];
  const u16t* r0 = p2t + ((size_t)b*SPTS + i0)*256 + l*8;
  const u16t* r1 = p2t + ((size_t)b*SPTS + i1)*256 + l*8;
  const u16t* r2 = p2t + ((size_t)b*SPTS + i2)*256 + l*8;
  uint4 q0 = *reinterpret_cast<const uint4*>(r0);
  uint4 q1 = *reinterpret_cast<const uint4*>(r1);
  uint4 q2 = *reinterpret_cast<const uint4*>(r2);
  const u32t* a0 = reinterpret_cast<const u32t*>(&q0);
  const u32t* a1 = reinterpret_cast<const u32t*>(&q1);
  const u32t* a2 = reinterpret_cast<const u32t*>(&q2);
  u32t ow[4];
  #pragma unroll
  for (int j = 0; j < 4; ++j){
    u32t u0 = a0[j], u1 = a1[j], u2 = a2[j];
    float lo = fmaf(w2, b2f((u16t)u2), fmaf(w1, b2f((u16t)u1), w0*b2f((u16t)u0)));
    float hi = fmaf(w2, b2f((u16t)(u2>>16)), fmaf(w1, b2f((u16t)(u1>>16)), w0*b2f((u16t)(u0>>16))));
    ow[j] = (u32t)f2b(lo) | ((u32t)f2b(hi) << 16);
  }
  *reinterpret_cast<uint4*>(it + (size_t)pid*256 + l*8) = make_uint4(ow[0], ow[1], ow[2], ow[3]);
}

// ---- MFMA conv1x1: OUT chans, row-stride YSTR, TILE=128; HALVES=2 fuses the M-split
//      into one dispatch (half = bid&1 -> co-resident halves; pointers offset in-kernel) ----
template<int CIN, int OUT, int YSTR, int TILE, int HALVES, bool SPLIT>
__global__ __launch_bounds__(256, 1) void mfma_conv_kernel(const u16t* __restrict__ xa, const u16t* __restrict__ xb,
                                                           const u16t* __restrict__ W, const float* __restrict__ bias,
                                                           u16t* __restrict__ y, float* __restrict__ partial,
                                                           const float* __restrict__ psipre, const float* __restrict__ stpsi,
                                                           const float* __restrict__ pbn_g, const float* __restrict__ pbn_b){
  constexpr int MW = OUT/4;
  constexpr int MF = MW/16;
  constexpr int NC = CIN/64;
  constexpr int NF = TILE/16;
  constexpr int NH = TILE/64;
  constexpr int SI = TILE/32;
  constexpr int CSTR = OUT + 8;
  constexpr int SBUF = TILE*64;
  constexpr int LDSE = (64*CSTR > 2*SBUF) ? 64*CSTR : 2*SBUF;
  __shared__ u16t lds[LDSE];
  int bid = blockIdx.x;
  int half = 0;
  if (HALVES == 2){ half = bid & 1; bid >>= 1; }
  const int tpb = NPTS/TILE;
  const int b = bid / tpb;
  const int n0 = (bid % tpb) * TILE;
  if (HALVES == 2){
    W += (size_t)half*OUT*CIN;
    bias += half*OUT;
    y += half*OUT;
    partial += (size_t)half * ((size_t)Bq*tpb*OUT*2);
  }
  const int wv = threadIdx.x >> 6;
  const int lane = threadIdx.x & 63;
  const int lr = lane & 15;
  const int kg = lane >> 4;
  const int m0 = wv * MW;
  const int t = threadIdx.x;

  float psiv[NF];
  if (SPLIT){
    float m  = stpsi[0]*(1.0f/CNTF);
    float vv = fmaxf(stpsi[1]*(1.0f/CNTF) - m*m, 0.0f);
    float iv = 1.0f/sqrtf(vv + BNEPS);
    float ap = pbn_g[0]*iv;
    float bp = pbn_b[0] - m*ap;
    #pragma unroll
    for (int nf = 0; nf < NF; ++nf){
      float z = fmaf(psipre[b*NPTS + n0 + nf*16 + lr], ap, bp);
      psiv[nf] = 1.0f/(1.0f + expf(-z));
    }
  }

  f32x4 acc[MF][NF];
  #pragma unroll
  for (int mf = 0; mf < MF; ++mf)
    #pragma unroll
    for (int nf = 0; nf < NF; ++nf){ acc[mf][nf][0]=0.f; acc[mf][nf][1]=0.f; acc[mf][nf][2]=0.f; acc[mf][nf][3]=0.f; }

  const u16t* wrow[MF];
  #pragma unroll
  for (int mf = 0; mf < MF; ++mf)
    wrow[mf] = W + (size_t)(m0 + mf*16 + lr)*CIN + kg*8;

  const int prow0 = wv*(TILE/4) + (lane>>3);
  const int gslot = (lane & 7) ^ ((lane >> 3) & 7);
  int rdoff[2][NF];
  #pragma unroll
  for (int ks = 0; ks < 2; ++ks)
    #pragma unroll
    for (int nf = 0; nf < NF; ++nf)
      rdoff[ks][nf] = (nf*16 + lr)*64 + (((ks*4 + kg) ^ (lr & 7)) << 3);

  auto stage = [&](int c, int buf){
    #pragma unroll
    for (int i = 0; i < SI; ++i){
      int p = prow0 + i*8;
      const u16t* g;
      if (SPLIT){
        if (c < 2) g = xa + ((size_t)b*NPTS + n0 + p)*128 + c*64     + gslot*8;
        else       g = xb + ((size_t)b*NPTS + n0 + p)*256 + (c-2)*64 + gslot*8;
      } else {
        g = xa + ((size_t)b*NPTS + n0 + p)*CIN + c*64 + gslot*8;
      }
      u16t* l = lds + buf*SBUF + (wv*(TILE/4) + i*8)*64;
      __builtin_amdgcn_global_load_lds(AS1(g), AS3(l), 16, 0, 0);
    }
  };

  stage(0, 0);
  __syncthreads();
  #pragma unroll
  for (int c = 0; c < NC; ++c){
    if (c + 1 < NC) stage(c+1, (c+1)&1);
    #pragma unroll
    for (int ks = 0; ks < 2; ++ks){
      const int k0 = c*2 + ks;
      s16x8 av[MF];
      #pragma unroll
      for (int mf = 0; mf < MF; ++mf)
        av[mf] = *reinterpret_cast<const s16x8*>(wrow[mf] + k0*32);
      #pragma unroll
      for (int h = 0; h < NF/4; ++h){
        s16x8 bv[4];
        #pragma unroll
        for (int j = 0; j < 4; ++j)
          bv[j] = *reinterpret_cast<const s16x8*>(lds + (c&1)*SBUF + rdoff[ks][h*4+j]);
        #pragma unroll
        for (int mf = 0; mf < MF; ++mf)
          #pragma unroll
          for (int j = 0; j < 4; ++j)
            acc[mf][h*4+j] = __builtin_amdgcn_mfma_f32_16x16x32_bf16(av[mf], bv[j], acc[mf][h*4+j], 0, 0, 0);
      }
    }
    if (SPLIT && c == 1){
      #pragma unroll
      for (int mf = 0; mf < MF; ++mf)
        #pragma unroll
        for (int nf = 0; nf < NF; ++nf){
          acc[mf][nf][0] *= psiv[nf]; acc[mf][nf][1] *= psiv[nf];
          acc[mf][nf][2] *= psiv[nf]; acc[mf][nf][3] *= psiv[nf];
        }
    }
    __syncthreads();
  }

  #pragma unroll
  for (int mf = 0; mf < MF; ++mf){
    int mb = m0 + mf*16 + kg*4;
    float4 bs = *reinterpret_cast<const float4*>(bias + mb);
    float s0=0.f,s1=0.f,s2=0.f,s3=0.f,q0=0.f,q1=0.f,q2=0.f,q3=0.f;
    #pragma unroll
    for (int nf = 0; nf < NF; ++nf){
      float v0 = acc[mf][nf][0] + bs.x;
      float v1 = acc[mf][nf][1] + bs.y;
      float v2 = acc[mf][nf][2] + bs.z;
      float v3 = acc[mf][nf][3] + bs.w;
      acc[mf][nf][0]=v0; acc[mf][nf][1]=v1; acc[mf][nf][2]=v2; acc[mf][nf][3]=v3;
      s0+=v0; q0+=v0*v0; s1+=v1; q1+=v1*v1;
      s2+=v2; q2+=v2*v2; s3+=v3; q3+=v3*v3;
    }
    #pragma unroll
    for (int o = 1; o < 16; o <<= 1){
      s0 += __shfl_xor(s0, o); s1 += __shfl_xor(s1, o);
      s2 += __shfl_xor(s2, o); s3 += __shfl_xor(s3, o);
      q0 += __shfl_xor(q0, o); q1 += __shfl_xor(q1, o);
      q2 += __shfl_xor(q2, o); q3 += __shfl_xor(q3, o);
    }
    if (lr == 0){
      float* pp = partial + (size_t)bid*(OUT*2) + mb*2;
      pp[0]=s0; pp[1]=q0; pp[2]=s1; pp[3]=q1;
      pp[4]=s2; pp[5]=q2; pp[6]=s3; pp[7]=q3;
    }
  }

  constexpr int CH8 = OUT/8;
  #pragma unroll
  for (int h = 0; h < NH; ++h){
    __syncthreads();
    #pragma unroll
    for (int mf = 0; mf < MF; ++mf){
      int mb = m0 + mf*16 + kg*4;
      #pragma unroll
      for (int j = 0; j < 4; ++j){
        int row = j*16 + lr;
        f32x4 v = acc[mf][h*4+j];
        uint2 pv;
        pv.x = (u32t)f2b(v[0]) | ((u32t)f2b(v[1]) << 16);
        pv.y = (u32t)f2b(v[2]) | ((u32t)f2b(v[3]) << 16);
        *reinterpret_cast<uint2*>(&lds[row*CSTR + mb]) = pv;
      }
    }
    __syncthreads();
    #pragma unroll
    for (int i = 0; i < (64*CH8)/256; ++i){
      int idx = t + i*256;
      int row = idx / CH8, c8 = idx % CH8;
      uint4 v = *reinterpret_cast<const uint4*>(&lds[row*CSTR + c8*8]);
      *reinterpret_cast<uint4*>(y + ((size_t)b*NPTS + n0 + h*64 + row)*YSTR + c8*8) = v;
    }
  }
}

// ---- reduce conv partials [NBLK][E] -> stats[E] (no atomics) ----
template<int E, int NBLK>
__global__ __launch_bounds__(256) void reduce_stats_kernel(const float* __restrict__ p, float* __restrict__ st){
  __shared__ float ls[8][32];
  const int t = threadIdx.x;
  const int kq = t >> 5, es = t & 31;
  const int e = blockIdx.x*32 + es;
  constexpr int R = NBLK/8;
  float s = 0.f;
  const float* pp = p + (size_t)kq*R*E + e;
  #pragma unroll 16
  for (int i = 0; i < R; ++i) s += pp[(size_t)i*E];
  ls[kq][es] = s;
  __syncthreads();
  if (kq == 0){
    st[e] = ((ls[0][es]+ls[1][es])+(ls[2][es]+ls[3][es]))
          + ((ls[4][es]+ls[5][es])+(ls[6][es]+ls[7][es]));
  }
}

// ---- gate ----
__global__ __launch_bounds__(256) void gate_kernel(const u16t* __restrict__ yg, const u16t* __restrict__ yx,
                                                   const float* __restrict__ stg, const float* __restrict__ stx,
                                                   const float* __restrict__ wg_bn_g, const float* __restrict__ wg_bn_b,
                                                   const float* __restrict__ wx_bn_g, const float* __restrict__ wx_bn_b,
                                                   const float* __restrict__ psi_w, const float* __restrict__ psi_b,
                                                   float* __restrict__ psipre, float* __restrict__ stpsi){
  __shared__ float lag[64], lbg[64], lax[64], lbx[64], lpw[64];
  __shared__ float red[8];
  const int t = threadIdx.x;
  if (t < 64){
    float m  = stg[t*2] * (1.0f/CNTF);
    float vv = fmaxf(stg[t*2+1]*(1.0f/CNTF) - m*m, 0.0f);
    float iv = 1.0f/sqrtf(vv + BNEPS);
    float gm = wg_bn_g[t];
    lag[t] = gm*iv; lbg[t] = wg_bn_b[t] - m*gm*iv;
    m  = stx[t*2] * (1.0f/CNTF);
    vv = fmaxf(stx[t*2+1]*(1.0f/CNTF) - m*m, 0.0f);
    iv = 1.0f/sqrtf(vv + BNEPS);
    gm = wx_bn_g[t];
    lax[t] = gm*iv; lbx[t] = wx_bn_b[t] - m*gm*iv;
    lpw[t] = psi_w[t];
  }
  __syncthreads();
  const int p = blockIdx.x*256 + t;
  const u16t* rg = yg + (size_t)p*64;
  const u16t* rx = yx + (size_t)p*64;
  float acc = psi_b[0];
  #pragma unroll
  for (int u = 0; u < 8; ++u){
    uint4 qg = *reinterpret_cast<const uint4*>(rg + u*8);
    uint4 qx = *reinterpret_cast<const uint4*>(rx + u*8);
    const u32t* g4 = reinterpret_cast<const u32t*>(&qg);
    const u32t* x4 = reinterpret_cast<const u32t*>(&qx);
    #pragma unroll
    for (int e = 0; e < 4; ++e){
      int j = u*8 + e*2;
      float gv0 = fmaf(b2f((u16t)g4[e]),        lag[j],   lbg[j]);
      float xv0 = fmaf(b2f((u16t)x4[e]),        lax[j],   lbx[j]);
      float gv1 = fmaf(b2f((u16t)(g4[e]>>16)),  lag[j+1], lbg[j+1]);
      float xv1 = fmaf(b2f((u16t)(x4[e]>>16)),  lax[j+1], lbx[j+1]);
      acc = fmaf(lpw[j],   lrelu(gv0 + xv0), acc);
      acc = fmaf(lpw[j+1], lrelu(gv1 + xv1), acc);
    }
  }
  psipre[p] = acc;
  float s = acc, q = acc*acc;
  #pragma unroll
  for (int o = 32; o; o >>= 1){ s += __shfl_xor(s, o); q += __shfl_xor(q, o); }
  if ((t & 63) == 0){ red[(t>>6)*2] = s; red[(t>>6)*2+1] = q; }
  __syncthreads();
  if (t == 0){
    atomicAdd(&stpsi[0], red[0]+red[2]+red[4]+red[6]);
    atomicAdd(&stpsi[1], red[1]+red[3]+red[5]+red[7]);
  }
}

// ---- bn1 + lrelu in place on h1 [P][256] bf16 ----
__global__ __launch_bounds__(256) void bnrelu256_kernel(u16t* __restrict__ x, const float* __restrict__ st,
                                                        const float* __restrict__ g, const float* __restrict__ bb){
  __shared__ float sa[256], sc[256];
  const int t = threadIdx.x;
  {
    float m  = st[t*2]*(1.0f/CNTF);
    float vv = fmaxf(st[t*2+1]*(1.0f/CNTF) - m*m, 0.0f);
    float iv = 1.0f/sqrtf(vv + BNEPS);
    float gm = g[t];
    sa[t] = gm*iv; sc[t] = bb[t] - m*gm*iv;
  }
  __syncthreads();
  size_t e4 = ((size_t)blockIdx.x*256 + t)*4;
  int c0 = (int)(e4 & 255);
  uint2 v = *reinterpret_cast<uint2*>(x + e4);
  float f0 = lrelu(fmaf(b2f((u16t)v.x),        sa[c0],   sc[c0]));
  float f1 = lrelu(fmaf(b2f((u16t)(v.x>>16)),  sa[c0+1], sc[c0+1]));
  float f2 = lrelu(fmaf(b2f((u16t)v.y),        sa[c0+2], sc[c0+2]));
  float f3 = lrelu(fmaf(b2f((u16t)(v.y>>16)),  sa[c0+3], sc[c0+3]));
  v.x = (u32t)f2b(f0) | ((u32t)f2b(f1) << 16);
  v.y = (u32t)f2b(f2) | ((u32t)f2b(f3) << 16);
  *reinterpret_cast<uint2*>(x + e4) = v;
}

// ---- final: out[b][m][n] f32 = lrelu(bn2(h2[b][n][m])) via LDS tile transpose ----
__global__ __launch_bounds__(256) void final_kernel(const u16t* __restrict__ h2, const float* __restrict__ st,
                                                    const float* __restrict__ g, const float* __restrict__ bb,
                                                    float* __restrict__ out){
  __shared__ float am[128], cm[128];
  __shared__ float tile[64][129];
  const int t = threadIdx.x;
  if (t < 128){
    float m  = st[t*2]*(1.0f/CNTF);
    float vv = fmaxf(st[t*2+1]*(1.0f/CNTF) - m*m, 0.0f);
    float iv = 1.0f/sqrtf(vv + BNEPS);
    float gm = g[t];
    am[t] = gm*iv; cm[t] = bb[t] - m*gm*iv;
  }
  __syncthreads();
  const int n0 = blockIdx.x * 64;
  const int b  = blockIdx.y;
  #pragma unroll
  for (int i = 0; i < 32; ++i){
    int idx = t + i*256;
    int mm = idx & 127, nn = idx >> 7;
    float v = fmaf(b2f(h2[((size_t)b*NPTS + n0 + nn)*128 + mm]), am[mm], cm[mm]);
    tile[nn][mm] = lrelu(v);
  }
  __syncthreads();
  #pragma unroll
  for (int i = 0; i < 32; ++i){
    int idx = t + i*256;
    int nn = idx & 63, mm = idx >> 6;
    out[((size_t)(b*128 + mm))*NPTS + n0 + nn] = tile[nn][mm];
  }
}

extern "C" void kernel_launch(void* const* d_in, const int* in_sizes, int n_in,
                              void* d_out, int out_size, void* d_ws, size_t ws_size,
                              hipStream_t stream){
  const float* xyz1    = (const float*)d_in[0];
  const float* xyz2    = (const float*)d_in[1];
  const float* points1 = (const float*)d_in[2];
  const float* points2 = (const float*)d_in[3];
  const float* conv1_w = (const float*)d_in[4];
  const float* conv1_b = (const float*)d_in[5];
  const float* bn1_g   = (const float*)d_in[6];
  const float* bn1_b   = (const float*)d_in[7];
  const float* conv2_w = (const float*)d_in[8];
  const float* conv2_b = (const float*)d_in[9];
  const float* bn2_g   = (const float*)d_in[10];
  const float* bn2_b   = (const float*)d_in[11];
  const float* wg_w    = (const float*)d_in[12];
  const float* wg_b    = (const float*)d_in[13];
  const float* wg_bn_g = (const float*)d_in[14];
  const float* wg_bn_b = (const float*)d_in[15];
  const float* wx_w    = (const float*)d_in[16];
  const float* wx_b    = (const float*)d_in[17];
  const float* wx_bn_g = (const float*)d_in[18];
  const float* wx_bn_b = (const float*)d_in[19];
  const float* psi_w   = (const float*)d_in[20];
  const float* psi_b   = (const float*)d_in[21];
  const float* psi_bn_g= (const float*)d_in[22];
  const float* psi_bn_b= (const float*)d_in[23];

  char* ws = (char*)d_ws;
  float* stats  = (float*)(ws + O_STATS);
  u16t*  wb     = (u16t*)(ws + O_WB);
  float* psipre = (float*)(ws + O_PSIPRE);
  float4* sp    = (float4*)(ws + O_SP);
  u16t*  p2t    = (u16t*)(ws + O_P2T);
  float* part   = (float*)(ws + O_PART);
  u16t*  p1t    = (u16t*)(ws + O_P1T);
  u16t*  itp    = (u16t*)(ws + O_INT);
  u16t*  h1t    = (u16t*)(ws + O_H1);
  float* pd     = (float*)(ws + O_PD);
  int*   pi     = (int*)(ws + O_PI);
  int*   idx3   = (int*)(ws + O_IDX3);
  float* w3     = (float*)(ws + O_W3);
  u16t*  ygt    = (u16t*)(ws + O_YG);
  u16t*  yxt    = (u16t*)(ws + O_YX);
  u16t*  h2t    = (u16t*)(ws + O_H2);

  hipMemsetAsync(ws + O_STATS, 0, 8192, stream);

  knn_prep_kernel<<<(Bq*SPTS)/256, 256, 0, stream>>>(xyz2, sp);
  knn_part_kernel<<<dim3(NPTS/256, NCH, Bq), 256, 0, stream>>>(xyz1, sp, pd, pi);
  knn_merge_kernel<<<(Bq*NPTS)/256, 256, 0, stream>>>(pd, pi, idx3, w3);
  tpose_kernel<256, SPTS><<<dim3(SPTS/64, 4, Bq), 256, 0, stream>>>(points2, p2t);
  interp_kernel<<<(Bq*NPTS)/8, 256, 0, stream>>>(p2t, idx3, w3, itp);
  tpose_kernel<128, NPTS><<<dim3(NPTS/64, 2, Bq), 256, 0, stream>>>(points1, p1t);
  wcvt_kernel<<<(WTOTAL+255)/256, 256, 0, stream>>>(conv1_w, conv2_w, wg_w, wx_w, wb);

  mfma_conv_kernel<256, 64, 64, 128, 1, false><<<Bq*(NPTS/128), 256, 0, stream>>>(itp, nullptr, wb+WOFF_WG, wg_b, ygt, part,
                                                                                  nullptr, nullptr, nullptr, nullptr);
  reduce_stats_kernel<128, 512><<<4, 256, 0, stream>>>(part, stats+ST_WG);
  mfma_conv_kernel<128, 64, 64, 128, 1, false><<<Bq*(NPTS/128), 256, 0, stream>>>(p1t, nullptr, wb+WOFF_WX, wx_b, yxt, part,
                                                                                  nullptr, nullptr, nullptr, nullptr);
  reduce_stats_kernel<128, 512><<<4, 256, 0, stream>>>(part, stats+ST_WX);
  gate_kernel<<<256, 256, 0, stream>>>(ygt, yxt, stats+ST_WG, stats+ST_WX,
                                       wg_bn_g, wg_bn_b, wx_bn_g, wx_bn_b,
                                       psi_w, psi_b, psipre, stats+ST_PSI);

  // conv1: M-split FUSED into one 1024-block dispatch (half = bid&1, co-resident halves)
  mfma_conv_kernel<384, 128, 256, 128, 2, true><<<2*Bq*(NPTS/128), 256, 0, stream>>>(
      p1t, itp, wb+WOFF_C1, conv1_b, h1t, part,
      psipre, stats+ST_PSI, psi_bn_g, psi_bn_b);
  reduce_stats_kernel<256, 512><<<8, 256, 0, stream>>>(part,           stats+ST_BN1);
  reduce_stats_kernel<256, 512><<<8, 256, 0, stream>>>(part + 131072,  stats+ST_BN1+256);
  bnrelu256_kernel<<<16384, 256, 0, stream>>>(h1t, stats+ST_BN1, bn1_g, bn1_b);

  mfma_conv_kernel<256, 128, 128, 128, 1, false><<<Bq*(NPTS/128), 256, 0, stream>>>(h1t, nullptr, wb+WOFF_C2, conv2_b, h2t, part,
                                                                                    nullptr, nullptr, nullptr, nullptr);
  reduce_stats_kernel<256, 512><<<8, 256, 0, stream>>>(part, stats+ST_BN2);
  final_kernel<<<dim3(NPTS/64, Bq), 256, 0, stream>>>(h2t, stats+ST_BN2, bn2_g, bn2_b, (float*)d_out);
}